// Round 4
// baseline (782.399 us; speedup 1.0000x reference)
//
#include <hip/hip_runtime.h>

// GNN layer (fp32 in/out):
//   out_i = (e_i@W1^T + b1 + b2) + dinv_i * sum_{j in N(i)} z_j
//   z_j   = dinv_j * (e_j@W1^T + e_j^2@W2^T)
// (algebraic refactor of: (e + L e)@W1^T + b1 + (L e^2)@W2^T + b2, L = D^-1/2 A D^-1/2)
// CSR build exploits symmetric edge layout row=[u;it], col=[it;u]: one pass over
// E/2 pairs emits both directions. z / y1b tables stored bf16 (halves gather bytes).

__device__ __forceinline__ float bf2f(unsigned short u) {
    union { unsigned int i; float f; } c; c.i = ((unsigned int)u) << 16; return c.f;
}
__device__ __forceinline__ unsigned short f2bf(float f) {
    union { float f; unsigned int i; } c; c.f = f;
    unsigned int r = c.i + 0x7FFFu + ((c.i >> 16) & 1u);  // RTN-even
    return (unsigned short)(r >> 16);
}

__global__ void k_deg(const int* __restrict__ row, const int* __restrict__ col,
                      int* __restrict__ deg, int Eh) {
    int e = blockIdx.x * blockDim.x + threadIdx.x;
    if (e < Eh) {
        atomicAdd(&deg[row[e]], 1);
        atomicAdd(&deg[col[e]], 1);
    }
}

// Exclusive scan of deg (1024 elems/block)
__global__ void k_scan1(const int* __restrict__ deg, int* __restrict__ part,
                        int* __restrict__ bsums, int n) {
    __shared__ int lds[256];
    int t = threadIdx.x;
    int base = blockIdx.x * 1024 + t * 4;
    int v0 = (base + 0 < n) ? deg[base + 0] : 0;
    int v1 = (base + 1 < n) ? deg[base + 1] : 0;
    int v2 = (base + 2 < n) ? deg[base + 2] : 0;
    int v3 = (base + 3 < n) ? deg[base + 3] : 0;
    int s = v0 + v1 + v2 + v3;
    lds[t] = s;
    __syncthreads();
    for (int off = 1; off < 256; off <<= 1) {
        int x = (t >= off) ? lds[t - off] : 0;
        __syncthreads();
        lds[t] += x;
        __syncthreads();
    }
    int excl = lds[t] - s;
    if (t == 255) bsums[blockIdx.x] = lds[255];
    int run = excl;
    if (base + 0 < n) { part[base + 0] = run; run += v0; }
    if (base + 1 < n) { part[base + 1] = run; run += v1; }
    if (base + 2 < n) { part[base + 2] = run; run += v2; }
    if (base + 3 < n) { part[base + 3] = run; }
}

// parallel exclusive scan of block sums (nblk=141 fits one 256-thread block)
__global__ void k_scan2(int* __restrict__ bsums, int nblk) {
    __shared__ int lds[256];
    int t = threadIdx.x;
    int v = (t < nblk) ? bsums[t] : 0;
    lds[t] = v;
    __syncthreads();
    for (int off = 1; off < 256; off <<= 1) {
        int x = (t >= off) ? lds[t - off] : 0;
        __syncthreads();
        lds[t] += x;
        __syncthreads();
    }
    if (t < nblk) bsums[t] = lds[t] - v;
    __syncthreads();
    if (t == 0 && nblk > 256) {  // defensive fallback, unused at n=144242
        int s = lds[255];
        for (int k = 256; k < nblk; k++) { int tmp = bsums[k]; bsums[k] = s; s += tmp; }
    }
}

// start/cursor from scan, dinv, and one-time interleaved weight buffer
// wBg[k2*64+d] = {W1[d][2k2], W2[d][2k2], W1[d][2k2+1], W2[d][2k2+1]}
__global__ void k_scan3(const int* __restrict__ part, const int* __restrict__ bsums,
                        const int* __restrict__ deg, float* __restrict__ dinv,
                        int* __restrict__ start, int* __restrict__ cursor,
                        const float* __restrict__ W1, const float* __restrict__ W2,
                        float4* __restrict__ wBg, int n, int E) {
    int i = blockIdx.x * blockDim.x + threadIdx.x;
    if (i < n) {
        int s = part[i] + bsums[i >> 10];
        start[i] = s;
        cursor[i] = s;
        int d = deg[i];
        dinv[i] = d > 0 ? rsqrtf((float)d) : 0.0f;
    }
    if (i == 0) start[n] = E;
    if (i < 2048) {
        int k2 = i >> 6, d = i & 63;
        wBg[i] = make_float4(W1[d * 64 + 2 * k2], W2[d * 64 + 2 * k2],
                             W1[d * 64 + 2 * k2 + 1], W2[d * 64 + 2 * k2 + 1]);
    }
}

__global__ void k_fill(const int* __restrict__ row, const int* __restrict__ col,
                       int* __restrict__ cursor, int* __restrict__ scol, int Eh) {
    int e = blockIdx.x * blockDim.x + threadIdx.x;
    if (e < Eh) {
        int u = row[e], v = col[e];
        scol[atomicAdd(&cursor[u], 1)] = v;
        scol[atomicAdd(&cursor[v], 1)] = u;
    }
}

// Per-node transform: y1b = e@W1^T + b1 + b2 (bf16), z = dinv*(e@W1^T + e^2@W2^T) (bf16)
// wave per node, lane = output dim; grid-stride so wB stages once per block.
__global__ __launch_bounds__(512, 8) void k_xform(
    const float* __restrict__ embed, const float* __restrict__ dinv,
    const float4* __restrict__ wBg, const float* __restrict__ b1,
    const float* __restrict__ b2, unsigned short* __restrict__ y1b,
    unsigned short* __restrict__ zb, int n) {
    __shared__ float4 wB[2048];          // [k2*64+d]
    __shared__ float2 ebuf[8][64];       // per-wave {e_k, e_k^2}
    int tid = threadIdx.x;
#pragma unroll
    for (int t = 0; t < 4; t++) wB[tid + 512 * t] = wBg[tid + 512 * t];
    __syncthreads();
    int wave = tid >> 6, lane = tid & 63;
    float bsum = b1[lane] + b2[lane];
    for (int i = blockIdx.x * 8 + wave; i < n; i += gridDim.x * 8) {
        float ev = embed[(size_t)i * 64 + lane];
        ebuf[wave][lane] = make_float2(ev, ev * ev);   // wave-internal; compiler orders
        const float4* eb = (const float4*)&ebuf[wave][0];
        float acc1 = 0.f, acc2 = 0.f;
#pragma unroll
        for (int k2 = 0; k2 < 32; k2++) {
            float4 w = wB[(k2 << 6) + lane];   // consecutive-lane b128: conflict-free
            float4 ee = eb[k2];                // uniform: broadcast
            acc1 = fmaf(ee.x, w.x, acc1);
            acc2 = fmaf(ee.y, w.y, acc2);
            acc1 = fmaf(ee.z, w.z, acc1);
            acc2 = fmaf(ee.w, w.w, acc2);
        }
        y1b[(size_t)i * 64 + lane] = f2bf(acc1 + bsum);
        zb[(size_t)i * 64 + lane]  = f2bf(dinv[i] * (acc1 + acc2));
    }
}

// Pure gather-sum: 16-lane group per node, 4 nodes/wave, no LDS, no syncthreads.
__global__ __launch_bounds__(256, 8) void k_main(
    const ushort4* __restrict__ zb4, const ushort4* __restrict__ y1b4,
    const int* __restrict__ start, const int* __restrict__ scol,
    const float* __restrict__ dinv, float4* __restrict__ out4, int n) {
    int tid = threadIdx.x;
    int wave = tid >> 6, lane = tid & 63, g = lane >> 4, l = lane & 15;
    int i = blockIdx.x * 16 + wave * 4 + g;
    bool valid = i < n;
    int ii = valid ? i : 0;
    int s0 = start[ii];
    int s1 = valid ? start[ii + 1] : s0;

    float4 acc = make_float4(0.f, 0.f, 0.f, 0.f);
    for (int e = s0; e < s1; e += 16) {
        int cnt = s1 - e;
        cnt = cnt > 16 ? 16 : cnt;
        int jv = scol[e + (l < cnt ? l : 0)];
#pragma unroll 8
        for (int k = 0; k < 16; k++) {
            int j = __shfl(jv, (g << 4) + k, 64);
            float m = (k < cnt) ? 1.0f : 0.0f;
            ushort4 z = zb4[(size_t)j * 16 + l];
            acc.x = fmaf(bf2f(z.x), m, acc.x);
            acc.y = fmaf(bf2f(z.y), m, acc.y);
            acc.z = fmaf(bf2f(z.z), m, acc.z);
            acc.w = fmaf(bf2f(z.w), m, acc.w);
        }
    }
    if (valid) {
        float di = dinv[i];
        ushort4 yb = y1b4[(size_t)i * 16 + l];
        float4 o;
        o.x = fmaf(di, acc.x, bf2f(yb.x));
        o.y = fmaf(di, acc.y, bf2f(yb.y));
        o.z = fmaf(di, acc.z, bf2f(yb.z));
        o.w = fmaf(di, acc.w, bf2f(yb.w));
        out4[(size_t)i * 16 + l] = o;
    }
}

extern "C" void kernel_launch(void* const* d_in, const int* in_sizes, int n_in,
                              void* d_out, int out_size, void* d_ws, size_t ws_size,
                              hipStream_t stream) {
    const float* embed = (const float*)d_in[0];
    const int* row = (const int*)d_in[1];
    const int* col = (const int*)d_in[2];
    const float* W1 = (const float*)d_in[3];
    const float* b1 = (const float*)d_in[4];
    const float* W2 = (const float*)d_in[5];
    const float* b2 = (const float*)d_in[6];
    float* out = (float*)d_out;

    int n = in_sizes[0] / 64;   // 144242
    int E = in_sizes[1];        // 2,000,000
    int Eh = E / 2;             // symmetric pairs: row=[u;it], col=[it;u]
    int nblk = (n + 1023) / 1024;
    size_t n64 = (size_t)n * 64;

    char* ws = (char*)d_ws;
    size_t off = 0;
    unsigned short* zb = (unsigned short*)(ws + off);  off += n64 * 2;   // 18.5 MB
    unsigned short* y1b = (unsigned short*)(ws + off); off += n64 * 2;   // 18.5 MB
    float4* wBg = (float4*)(ws + off);                 off += 2048 * 16;
    int* scol = (int*)(ws + off);                      off += (size_t)E * 4;
    int* deg = (int*)(ws + off);                       off += (size_t)n * 4;
    float* dinv = (float*)(ws + off);                  off += (size_t)n * 4;
    int* part = (int*)(ws + off);                      off += (size_t)n * 4;
    int* bsums = (int*)(ws + off);                     off += (size_t)(nblk + 1) * 4;
    int* start = (int*)(ws + off);                     off += (size_t)(n + 1) * 4;
    int* cursor = (int*)(ws + off);                    off += (size_t)n * 4;

    if (off > ws_size) return;  // ws too small -> out stays zero (0.707 absmax signal)

    hipMemsetAsync(deg, 0, (size_t)n * 4, stream);
    k_deg<<<(Eh + 255) / 256, 256, 0, stream>>>(row, col, deg, Eh);
    k_scan1<<<nblk, 256, 0, stream>>>(deg, part, bsums, n);
    k_scan2<<<1, 256, 0, stream>>>(bsums, nblk);
    k_scan3<<<(n + 255) / 256, 256, 0, stream>>>(part, bsums, deg, dinv, start,
                                                 cursor, W1, W2, wBg, n, E);
    k_fill<<<(Eh + 255) / 256, 256, 0, stream>>>(row, col, cursor, scol, Eh);
    k_xform<<<2048, 512, 0, stream>>>(embed, dinv, wBg, b1, b2, y1b, zb, n);
    k_main<<<(n + 15) / 16, 256, 0, stream>>>((const ushort4*)zb, (const ushort4*)y1b,
                                              start, scol, dinv, (float4*)out, n);
}

// Round 5
// 359.720 us; speedup vs baseline: 2.1750x; 2.1750x over previous
//
#include <hip/hip_runtime.h>

// GNN layer (fp32 in/out):
//   out_i = (e_i@W1^T + b1 + b2) + dinv_i * sum_{j in N(i)} z_j
//   z_j   = dinv_j * (e_j@W1^T + e_j^2@W2^T)
// (algebraic refactor of: (e + L e)@W1^T + b1 + (L e^2)@W2^T + b2, L = D^-1/2 A D^-1/2)
// CSR build exploits symmetric edge layout row=[u;it], col=[it;u]. z / y1b tables
// stored bf16, but ALWAYS written as packed dwords (2-byte global stores trigger
// ECC read-modify-write amplification: round-4 measured 1.5 GB fetch for 37 MB of
// ushort stores).

__device__ __forceinline__ float bf2f(unsigned short u) {
    union { unsigned int i; float f; } c; c.i = ((unsigned int)u) << 16; return c.f;
}
__device__ __forceinline__ unsigned int f2bf(float f) {
    union { float f; unsigned int i; } c; c.f = f;
    unsigned int r = c.i + 0x7FFFu + ((c.i >> 16) & 1u);  // RTN-even
    return r >> 16;
}

__global__ void k_deg(const int* __restrict__ row, const int* __restrict__ col,
                      int* __restrict__ deg, int Eh) {
    int e = blockIdx.x * blockDim.x + threadIdx.x;
    if (e < Eh) {
        atomicAdd(&deg[row[e]], 1);
        atomicAdd(&deg[col[e]], 1);
    }
}

// Exclusive scan of deg (1024 elems/block)
__global__ void k_scan1(const int* __restrict__ deg, int* __restrict__ part,
                        int* __restrict__ bsums, int n) {
    __shared__ int lds[256];
    int t = threadIdx.x;
    int base = blockIdx.x * 1024 + t * 4;
    int v0 = (base + 0 < n) ? deg[base + 0] : 0;
    int v1 = (base + 1 < n) ? deg[base + 1] : 0;
    int v2 = (base + 2 < n) ? deg[base + 2] : 0;
    int v3 = (base + 3 < n) ? deg[base + 3] : 0;
    int s = v0 + v1 + v2 + v3;
    lds[t] = s;
    __syncthreads();
    for (int off = 1; off < 256; off <<= 1) {
        int x = (t >= off) ? lds[t - off] : 0;
        __syncthreads();
        lds[t] += x;
        __syncthreads();
    }
    int excl = lds[t] - s;
    if (t == 255) bsums[blockIdx.x] = lds[255];
    int run = excl;
    if (base + 0 < n) { part[base + 0] = run; run += v0; }
    if (base + 1 < n) { part[base + 1] = run; run += v1; }
    if (base + 2 < n) { part[base + 2] = run; run += v2; }
    if (base + 3 < n) { part[base + 3] = run; }
}

// parallel exclusive scan of block sums (nblk=141 fits one 256-thread block)
__global__ void k_scan2(int* __restrict__ bsums, int nblk) {
    __shared__ int lds[256];
    int t = threadIdx.x;
    int v = (t < nblk) ? bsums[t] : 0;
    lds[t] = v;
    __syncthreads();
    for (int off = 1; off < 256; off <<= 1) {
        int x = (t >= off) ? lds[t - off] : 0;
        __syncthreads();
        lds[t] += x;
        __syncthreads();
    }
    if (t < nblk) bsums[t] = lds[t] - v;
    __syncthreads();
    if (t == 0 && nblk > 256) {  // defensive fallback, unused at n=144242
        int s = lds[255];
        for (int k = 256; k < nblk; k++) { int tmp = bsums[k]; bsums[k] = s; s += tmp; }
    }
}

// start/cursor, dinv, and interleaved weight buffer
// wBg[k*32+q] = {W1[2q][k], W2[2q][k], W1[2q+1][k], W2[2q+1][k]}
__global__ void k_scan3(const int* __restrict__ part, const int* __restrict__ bsums,
                        const int* __restrict__ deg, float* __restrict__ dinv,
                        int* __restrict__ start, int* __restrict__ cursor,
                        const float* __restrict__ W1, const float* __restrict__ W2,
                        float4* __restrict__ wBg, int n, int E) {
    int i = blockIdx.x * blockDim.x + threadIdx.x;
    if (i < n) {
        int s = part[i] + bsums[i >> 10];
        start[i] = s;
        cursor[i] = s;
        int d = deg[i];
        dinv[i] = d > 0 ? rsqrtf((float)d) : 0.0f;
    }
    if (i == 0) start[n] = E;
    if (i < 2048) {
        int k = i >> 5, q = i & 31;
        wBg[i] = make_float4(W1[(2 * q) * 64 + k], W2[(2 * q) * 64 + k],
                             W1[(2 * q + 1) * 64 + k], W2[(2 * q + 1) * 64 + k]);
    }
}

__global__ void k_fill(const int* __restrict__ row, const int* __restrict__ col,
                       int* __restrict__ cursor, int* __restrict__ scol, int Eh) {
    int e = blockIdx.x * blockDim.x + threadIdx.x;
    if (e < Eh) {
        int u = row[e], v = col[e];
        scol[atomicAdd(&cursor[u], 1)] = v;
        scol[atomicAdd(&cursor[v], 1)] = u;
    }
}

// Per-node transform: y1p = pack2(e@W1^T + b1 + b2), zp = pack2(dinv*(e@W1^T + e^2@W2^T))
// Half-wave per node: lane q in [0,32) computes output dims 2q, 2q+1; dword stores.
__global__ __launch_bounds__(512, 8) void k_xform(
    const float2* __restrict__ embed2, const float* __restrict__ dinv,
    const float4* __restrict__ wBg, const float* __restrict__ b1,
    const float* __restrict__ b2, unsigned int* __restrict__ y1p,
    unsigned int* __restrict__ zp, int n) {
    __shared__ float4 wB[2048];        // [k*32+q]
    __shared__ float4 ebuf[8][2][32];  // [wave][half][q] = {e2q, e2q^2, e2q+1, e2q+1^2}
    int tid = threadIdx.x;
#pragma unroll
    for (int t = 0; t < 4; t++) wB[tid + 512 * t] = wBg[tid + 512 * t];
    __syncthreads();
    int wave = tid >> 6, lane = tid & 63, half = lane >> 5, q = lane & 31;
    float bs0 = b1[2 * q] + b2[2 * q];
    float bs1 = b1[2 * q + 1] + b2[2 * q + 1];
    for (int ip = blockIdx.x * 16 + wave * 2; ip < n; ip += gridDim.x * 16) {
        int i = ip + half;
        int ic = i < n ? i : n - 1;
        float2 ev = embed2[(size_t)ic * 32 + q];
        ebuf[wave][half][q] = make_float4(ev.x, ev.x * ev.x, ev.y, ev.y * ev.y);
        const float2* eb = (const float2*)&ebuf[wave][half][0];  // [k] = {e_k, e_k^2}
        float y0 = 0.f, s0 = 0.f, y1 = 0.f, s1 = 0.f;
#pragma unroll
        for (int k = 0; k < 64; k++) {
            float4 w = wB[(k << 5) + q];   // b128, consecutive lanes: conflict-free
            float2 ee = eb[k];             // uniform per half-wave: broadcast
            y0 = fmaf(ee.x, w.x, y0);
            s0 = fmaf(ee.y, w.y, s0);
            y1 = fmaf(ee.x, w.z, y1);
            s1 = fmaf(ee.y, w.w, s1);
        }
        if (i < n) {
            float di = dinv[i];
            y1p[(size_t)i * 32 + q] = f2bf(y0 + bs0) | (f2bf(y1 + bs1) << 16);
            zp[(size_t)i * 32 + q] = f2bf(di * (y0 + s0)) | (f2bf(di * (y1 + s1)) << 16);
        }
    }
}

// Pure gather-sum: 16-lane group per node, 4 nodes/wave, no LDS, no syncthreads.
__global__ __launch_bounds__(256, 8) void k_main(
    const ushort4* __restrict__ zb4, const ushort4* __restrict__ y1b4,
    const int* __restrict__ start, const int* __restrict__ scol,
    const float* __restrict__ dinv, float4* __restrict__ out4, int n) {
    int tid = threadIdx.x;
    int wave = tid >> 6, lane = tid & 63, g = lane >> 4, l = lane & 15;
    int i = blockIdx.x * 16 + wave * 4 + g;
    bool valid = i < n;
    int ii = valid ? i : 0;
    int s0 = start[ii];
    int s1 = valid ? start[ii + 1] : s0;

    float4 acc = make_float4(0.f, 0.f, 0.f, 0.f);
    for (int e = s0; e < s1; e += 16) {
        int cnt = s1 - e;
        cnt = cnt > 16 ? 16 : cnt;
        int jv = scol[e + (l < cnt ? l : 0)];
#pragma unroll 8
        for (int k = 0; k < 16; k++) {
            int j = __shfl(jv, (g << 4) + k, 64);
            float m = (k < cnt) ? 1.0f : 0.0f;
            ushort4 z = zb4[(size_t)j * 16 + l];
            acc.x = fmaf(bf2f(z.x), m, acc.x);
            acc.y = fmaf(bf2f(z.y), m, acc.y);
            acc.z = fmaf(bf2f(z.z), m, acc.z);
            acc.w = fmaf(bf2f(z.w), m, acc.w);
        }
    }
    if (valid) {
        float di = dinv[i];
        ushort4 yb = y1b4[(size_t)i * 16 + l];
        float4 o;
        o.x = fmaf(di, acc.x, bf2f(yb.x));
        o.y = fmaf(di, acc.y, bf2f(yb.y));
        o.z = fmaf(di, acc.z, bf2f(yb.z));
        o.w = fmaf(di, acc.w, bf2f(yb.w));
        out4[(size_t)i * 16 + l] = o;
    }
}

extern "C" void kernel_launch(void* const* d_in, const int* in_sizes, int n_in,
                              void* d_out, int out_size, void* d_ws, size_t ws_size,
                              hipStream_t stream) {
    const float* embed = (const float*)d_in[0];
    const int* row = (const int*)d_in[1];
    const int* col = (const int*)d_in[2];
    const float* W1 = (const float*)d_in[3];
    const float* b1 = (const float*)d_in[4];
    const float* W2 = (const float*)d_in[5];
    const float* b2 = (const float*)d_in[6];
    float* out = (float*)d_out;

    int n = in_sizes[0] / 64;   // 144242
    int E = in_sizes[1];        // 2,000,000
    int Eh = E / 2;             // symmetric pairs: row=[u;it], col=[it;u]
    int nblk = (n + 1023) / 1024;
    size_t n64 = (size_t)n * 64;

    char* ws = (char*)d_ws;
    size_t off = 0;
    unsigned int* zp = (unsigned int*)(ws + off);  off += n64 * 2;   // 18.5 MB
    unsigned int* y1p = (unsigned int*)(ws + off); off += n64 * 2;   // 18.5 MB
    float4* wBg = (float4*)(ws + off);             off += 2048 * 16;
    int* scol = (int*)(ws + off);                  off += (size_t)E * 4;
    int* deg = (int*)(ws + off);                   off += (size_t)n * 4;
    float* dinv = (float*)(ws + off);              off += (size_t)n * 4;
    int* part = (int*)(ws + off);                  off += (size_t)n * 4;
    int* bsums = (int*)(ws + off);                 off += (size_t)(nblk + 1) * 4;
    int* start = (int*)(ws + off);                 off += (size_t)(n + 1) * 4;
    int* cursor = (int*)(ws + off);                off += (size_t)n * 4;

    if (off > ws_size) return;  // ws too small -> out stays zero (0.707 absmax signal)

    hipMemsetAsync(deg, 0, (size_t)n * 4, stream);
    k_deg<<<(Eh + 255) / 256, 256, 0, stream>>>(row, col, deg, Eh);
    k_scan1<<<nblk, 256, 0, stream>>>(deg, part, bsums, n);
    k_scan2<<<1, 256, 0, stream>>>(bsums, nblk);
    k_scan3<<<(n + 255) / 256, 256, 0, stream>>>(part, bsums, deg, dinv, start,
                                                 cursor, W1, W2, wBg, n, E);
    k_fill<<<(Eh + 255) / 256, 256, 0, stream>>>(row, col, cursor, scol, Eh);
    k_xform<<<2048, 512, 0, stream>>>((const float2*)embed, dinv, wBg, b1, b2,
                                      y1p, zp, n);
    k_main<<<(n + 15) / 16, 256, 0, stream>>>((const ushort4*)zp, (const ushort4*)y1p,
                                              start, scol, dinv, (float4*)out, n);
}